// Round 9
// baseline (288.892 us; speedup 1.0000x reference)
//
#include <hip/hip_runtime.h>
#include <math.h>

#define NBINS 15
#define THREADS 256
#define GRID 2048          // 8 blocks/CU * 256 CUs; exactly 8 iters/thread at N=2^24
#define BIN_LO 4           // C=3 => conf >= 1/3 => bins 4..14 only
#define NACC (NBINS - BIN_LO)
#define CTR_OFF (NACC * GRID * sizeof(float))  // counter placed after partials in d_ws

__device__ __forceinline__ void process_row(float l0, float l1, float l2, int lab,
                                            float* a) {
  float m  = fmaxf(fmaxf(l0, l1), l2);            // v_max3_f32
  float md = __builtin_amdgcn_fmed3f(l0, l1, l2); // median
  float mn = fminf(fminf(l0, l1), l2);            // v_min3_f32
  float s  = 1.0f + __expf(md - m) + __expf(mn - m);  // exp(max-max)=1 for free
  float conf = __builtin_amdgcn_rcpf(s);          // max prob = 1/s
  // correct <=> logit[label] equals the max (ties measure-zero; ECE effect ~6e-8)
  float lm = (lab == 1) ? l1 : ((lab == 2) ? l2 : l0);
  float val = conf - ((lm >= m) ? 1.0f : 0.0f);
  // bin i covers (i/15,(i+1)/15]; searchsorted(uppers,conf,'left') == ceil(conf*15)-1
  int bin = (int)ceilf(conf * 15.0f) - 1;
  bin = bin < BIN_LO ? BIN_LO : (bin > NBINS - 1 ? NBINS - 1 : bin);
#pragma unroll
  for (int b = BIN_LO; b < NBINS; ++b) a[b - BIN_LO] += (bin == b) ? val : 0.0f;
}

__global__ __launch_bounds__(THREADS, 8) void ece_main(
    const float4* __restrict__ logits4, const int4* __restrict__ labels4,
    float* __restrict__ partial, unsigned int* __restrict__ ctr,
    float* __restrict__ out, int n) {
  float a[NACC];
#pragma unroll
  for (int i = 0; i < NACC; ++i) a[i] = 0.0f;

  const int nquads = n >> 2;
  const int total = gridDim.x * blockDim.x;
  const int iters = nquads / total;  // uniform trip count (8 for N=2^24)
  int q = blockIdx.x * blockDim.x + threadIdx.x;
#pragma unroll 2
  for (int it = 0; it < iters; ++it, q += total) {
    const float4* p = logits4 + 3 * (size_t)q;
    float4 x = p[0], y = p[1], z = p[2];
    int4 lb = labels4[q];
    process_row(x.x, x.y, x.z, lb.x, a);
    process_row(x.w, y.x, y.y, lb.y, a);
    process_row(y.z, y.w, z.x, lb.z, a);
    process_row(z.y, z.z, z.w, lb.w, a);
  }
  if (q < nquads) {  // remainder quads when total doesn't divide nquads
    const float4* p = logits4 + 3 * (size_t)q;
    float4 x = p[0], y = p[1], z = p[2];
    int4 lb = labels4[q];
    process_row(x.x, x.y, x.z, lb.x, a);
    process_row(x.w, y.x, y.y, lb.y, a);
    process_row(y.z, y.w, z.x, lb.z, a);
    process_row(z.y, z.z, z.w, lb.w, a);
  }

  // wave butterfly reduce, then cross-wave via tiny LDS
#pragma unroll
  for (int i = 0; i < NACC; ++i) {
    float v = a[i];
#pragma unroll
    for (int off = 32; off > 0; off >>= 1) v += __shfl_down(v, off, 64);
    a[i] = v;
  }
  __shared__ float s_part[THREADS / 64][NACC];
  __shared__ bool s_last;
  const int wave = threadIdx.x >> 6;
  const int lane = threadIdx.x & 63;
  if (lane == 0) {
#pragma unroll
    for (int i = 0; i < NACC; ++i) s_part[wave][i] = a[i];
  }
  __syncthreads();
  if (threadIdx.x < NACC) {
    float v = 0.0f;
#pragma unroll
    for (int w = 0; w < THREADS / 64; ++w) v += s_part[w][threadIdx.x];
    partial[(size_t)threadIdx.x * gridDim.x + blockIdx.x] = v;
  }

  // release: make partial[] visible device-wide, then signal (rocPRIM pattern)
  __threadfence();
  __syncthreads();
  if (threadIdx.x == 0) {
    unsigned int old = atomicAdd(ctr, 1u);
    s_last = (old == gridDim.x - 1);
  }
  __syncthreads();
  if (!s_last) return;
  __threadfence();  // acquire side

  // ---- final reduce: runs in exactly one (the last) block ----
  // 4 waves cover NACC=11 bins via stride-4 loop (R8 bug: `if (wave<NACC)`
  // left sbin[4..10] uninitialized with only 4 waves in the block)
  __shared__ double sbin[NACC];
  for (int b = wave; b < NACC; b += THREADS / 64) {
    const float4* pb = (const float4*)(partial + (size_t)b * gridDim.x);
    const int nq4 = gridDim.x >> 2;  // 512 float4s of partials per bin
    double v = 0.0;
    for (int i = lane; i < nq4; i += 64) {
      float4 t = pb[i];
      v += (double)t.x + (double)t.y + (double)t.z + (double)t.w;
    }
#pragma unroll
    for (int off = 32; off > 0; off >>= 1) v += __shfl_down(v, off, 64);
    if (lane == 0) sbin[b] = v;
  }
  __syncthreads();
  if (threadIdx.x == 0) {
    float t[NACC];
#pragma unroll
    for (int i = 0; i < NACC; ++i) t[i] = 0.0f;
    const float* lf = (const float*)logits4;
    const int* li = (const int*)labels4;
    for (int r = (n >> 2) << 2; r < n; ++r)  // tail rows (none for N=2^24)
      process_row(lf[3 * r], lf[3 * r + 1], lf[3 * r + 2], li[r], t);
    double ece = 0.0;
#pragma unroll
    for (int b = 0; b < NACC; ++b) ece += fabs(sbin[b] + (double)t[b]);
    out[0] = (float)(ece / (double)n);
  }
}

extern "C" void kernel_launch(void* const* d_in, const int* in_sizes, int n_in,
                              void* d_out, int out_size, void* d_ws, size_t ws_size,
                              hipStream_t stream) {
  const float4* logits4 = (const float4*)d_in[0];
  const int4* labels4 = (const int4*)d_in[1];
  const int n = in_sizes[1];  // rows == number of labels
  float* partial = (float*)d_ws;                           // [NACC][GRID]
  unsigned int* ctr = (unsigned int*)((char*)d_ws + CTR_OFF);
  hipMemsetAsync(ctr, 0, sizeof(unsigned int), stream);    // counter must start at 0
  ece_main<<<GRID, THREADS, 0, stream>>>(logits4, labels4, partial, ctr,
                                         (float*)d_out, n);
}

// Round 10
// 78.278 us; speedup vs baseline: 3.6906x; 3.6906x over previous
//
#include <hip/hip_runtime.h>
#include <math.h>

#define NBINS 15
#define THREADS 256
#define GRID 2048          // 8 blocks/CU * 256 CUs; exactly 8 iters/thread at N=2^24
#define BIN_LO 4           // C=3 => conf >= 1/3 => bins 4..14 only
#define NACC (NBINS - BIN_LO)

// d_ws layout: double d[NACC] @0 (88 B), unsigned ctr @88; memset 96 B per call.

__device__ __forceinline__ void process_row(float l0, float l1, float l2, int lab,
                                            float* a) {
  float m  = fmaxf(fmaxf(l0, l1), l2);            // v_max3_f32
  float md = __builtin_amdgcn_fmed3f(l0, l1, l2); // median
  float mn = fminf(fminf(l0, l1), l2);            // v_min3_f32
  float s  = 1.0f + __expf(md - m) + __expf(mn - m);  // exp(max-max)=1 for free
  float conf = __builtin_amdgcn_rcpf(s);          // max prob = 1/s
  // correct <=> logit[label] equals the max (ties measure-zero; ECE effect ~6e-8)
  float lm = (lab == 1) ? l1 : ((lab == 2) ? l2 : l0);
  float val = conf - ((lm >= m) ? 1.0f : 0.0f);
  // bin i covers (i/15,(i+1)/15]; searchsorted(uppers,conf,'left') == ceil(conf*15)-1
  int bin = (int)ceilf(conf * 15.0f) - 1;
  bin = bin < BIN_LO ? BIN_LO : (bin > NBINS - 1 ? NBINS - 1 : bin);
#pragma unroll
  for (int b = BIN_LO; b < NBINS; ++b) a[b - BIN_LO] += (bin == b) ? val : 0.0f;
}

__global__ __launch_bounds__(THREADS, 8) void ece_main(
    const float4* __restrict__ logits4, const int4* __restrict__ labels4,
    double* __restrict__ wsd, unsigned int* __restrict__ ctr,
    float* __restrict__ out, int n) {
  float a[NACC];
#pragma unroll
  for (int i = 0; i < NACC; ++i) a[i] = 0.0f;

  const int nquads = n >> 2;
  const int total = gridDim.x * blockDim.x;
  const int iters = nquads / total;  // uniform trip count (8 for N=2^24)
  int q = blockIdx.x * blockDim.x + threadIdx.x;
#pragma unroll 2
  for (int it = 0; it < iters; ++it, q += total) {
    const float4* p = logits4 + 3 * (size_t)q;
    float4 x = p[0], y = p[1], z = p[2];
    int4 lb = labels4[q];
    process_row(x.x, x.y, x.z, lb.x, a);
    process_row(x.w, y.x, y.y, lb.y, a);
    process_row(y.z, y.w, z.x, lb.z, a);
    process_row(z.y, z.z, z.w, lb.w, a);
  }
  if (q < nquads) {  // remainder quads when total doesn't divide nquads
    const float4* p = logits4 + 3 * (size_t)q;
    float4 x = p[0], y = p[1], z = p[2];
    int4 lb = labels4[q];
    process_row(x.x, x.y, x.z, lb.x, a);
    process_row(x.w, y.x, y.y, lb.y, a);
    process_row(y.z, y.w, z.x, lb.z, a);
    process_row(z.y, z.z, z.w, lb.w, a);
  }

  // wave butterfly reduce, then cross-wave via tiny LDS
#pragma unroll
  for (int i = 0; i < NACC; ++i) {
    float v = a[i];
#pragma unroll
    for (int off = 32; off > 0; off >>= 1) v += __shfl_down(v, off, 64);
    a[i] = v;
  }
  __shared__ float s_part[THREADS / 64][NACC];
  const int wave = threadIdx.x >> 6;
  const int lane = threadIdx.x & 63;
  if (lane == 0) {
#pragma unroll
    for (int i = 0; i < NACC; ++i) s_part[wave][i] = a[i];
  }
  __syncthreads();
  if (wave != 0) return;

  // --- wave 0 only: publish block totals via device-scope atomics (sc1,
  // coherence-point — NO cache-flushing __threadfence needed) ---
  if (lane < NACC) {
    float v = 0.0f;
#pragma unroll
    for (int w = 0; w < THREADS / 64; ++w) v += s_part[w][lane];
    atomicAdd(&wsd[lane], (double)v);
  }
  // completion (not flush): d-atomics ack'd at coherence point before ctr bump
  asm volatile("s_waitcnt vmcnt(0)" ::: "memory");
  unsigned int old = 0;
  if (lane == 0) old = atomicAdd(ctr, 1u);
  old = __shfl(old, 0, 64);
  if (old != (unsigned int)(gridDim.x - 1)) return;

  // --- last block, lane 0: tiny epilogue ---
  if (lane == 0) {
    double ece = 0.0;
    const int tail_lo = (n >> 2) << 2;
    if (tail_lo == n) {
#pragma unroll
      for (int b = 0; b < NACC; ++b) {
        double d = __hip_atomic_load(&wsd[b], __ATOMIC_RELAXED,
                                     __HIP_MEMORY_SCOPE_AGENT);
        ece += fabs(d);
      }
    } else {  // cold: fold tail rows (none for N=2^24)
      float t[NACC];
#pragma unroll
      for (int i = 0; i < NACC; ++i) t[i] = 0.0f;
      const float* lf = (const float*)logits4;
      const int* li = (const int*)labels4;
      for (int r = tail_lo; r < n; ++r)
        process_row(lf[3 * r], lf[3 * r + 1], lf[3 * r + 2], li[r], t);
#pragma unroll
      for (int b = 0; b < NACC; ++b) {
        double d = __hip_atomic_load(&wsd[b], __ATOMIC_RELAXED,
                                     __HIP_MEMORY_SCOPE_AGENT);
        ece += fabs(d + (double)t[b]);
      }
    }
    out[0] = (float)(ece / (double)n);
  }
}

extern "C" void kernel_launch(void* const* d_in, const int* in_sizes, int n_in,
                              void* d_out, int out_size, void* d_ws, size_t ws_size,
                              hipStream_t stream) {
  const float4* logits4 = (const float4*)d_in[0];
  const int4* labels4 = (const int4*)d_in[1];
  const int n = in_sizes[1];  // rows == number of labels
  double* wsd = (double*)d_ws;
  unsigned int* ctr = (unsigned int*)((char*)d_ws + NACC * sizeof(double));
  hipMemsetAsync(d_ws, 0, 96, stream);  // zero d[] and ctr every call
  ece_main<<<GRID, THREADS, 0, stream>>>(logits4, labels4, wsd, ctr,
                                         (float*)d_out, n);
}

// Round 11
// 57.864 us; speedup vs baseline: 4.9926x; 1.3528x over previous
//
#include <hip/hip_runtime.h>
#include <math.h>

#define NBINS 15
#define THREADS 256
#define GRID 2048          // 8 blocks/CU * 256 CUs; exactly 8 iters/thread at N=2^24
#define BIN_LO 4           // C=3 => conf >= 1/3 => bins 4..14 only
#define NACC (NBINS - BIN_LO)

__device__ __forceinline__ void process_row(float l0, float l1, float l2, int lab,
                                            float* a) {
  float m  = fmaxf(fmaxf(l0, l1), l2);            // v_max3_f32
  float md = __builtin_amdgcn_fmed3f(l0, l1, l2); // median
  float mn = fminf(fminf(l0, l1), l2);            // v_min3_f32
  float s  = 1.0f + __expf(md - m) + __expf(mn - m);  // exp(max-max)=1 for free
  float conf = __builtin_amdgcn_rcpf(s);          // max prob = 1/s
  // correct <=> logit[label] equals the max (ties measure-zero; ECE effect ~6e-8)
  float lm = (lab == 1) ? l1 : ((lab == 2) ? l2 : l0);
  float val = conf - ((lm >= m) ? 1.0f : 0.0f);
  // bin i covers (i/15,(i+1)/15]; searchsorted(uppers,conf,'left') == ceil(conf*15)-1
  int bin = (int)ceilf(conf * 15.0f) - 1;
  bin = bin < BIN_LO ? BIN_LO : (bin > NBINS - 1 ? NBINS - 1 : bin);
#pragma unroll
  for (int b = BIN_LO; b < NBINS; ++b) a[b - BIN_LO] += (bin == b) ? val : 0.0f;
}

__global__ __launch_bounds__(THREADS, 8) void ece_main(
    const float4* __restrict__ logits4, const int4* __restrict__ labels4,
    float* __restrict__ partial, int n) {
  float a[NACC];
#pragma unroll
  for (int i = 0; i < NACC; ++i) a[i] = 0.0f;

  const int nquads = n >> 2;
  const int total = gridDim.x * blockDim.x;
  const int iters = nquads / total;  // uniform trip count (8 for N=2^24)
  int q = blockIdx.x * blockDim.x + threadIdx.x;
#pragma unroll 2
  for (int it = 0; it < iters; ++it, q += total) {
    const float4* p = logits4 + 3 * (size_t)q;
    float4 x = p[0], y = p[1], z = p[2];
    int4 lb = labels4[q];
    process_row(x.x, x.y, x.z, lb.x, a);
    process_row(x.w, y.x, y.y, lb.y, a);
    process_row(y.z, y.w, z.x, lb.z, a);
    process_row(z.y, z.z, z.w, lb.w, a);
  }
  if (q < nquads) {  // remainder quads when total doesn't divide nquads
    const float4* p = logits4 + 3 * (size_t)q;
    float4 x = p[0], y = p[1], z = p[2];
    int4 lb = labels4[q];
    process_row(x.x, x.y, x.z, lb.x, a);
    process_row(x.w, y.x, y.y, lb.y, a);
    process_row(y.z, y.w, z.x, lb.z, a);
    process_row(z.y, z.z, z.w, lb.w, a);
  }

  // wave butterfly reduce, then cross-wave via tiny LDS
#pragma unroll
  for (int i = 0; i < NACC; ++i) {
    float v = a[i];
#pragma unroll
    for (int off = 32; off > 0; off >>= 1) v += __shfl_down(v, off, 64);
    a[i] = v;
  }
  __shared__ float s_part[THREADS / 64][NACC];
  const int wave = threadIdx.x >> 6;
  const int lane = threadIdx.x & 63;
  if (lane == 0) {
#pragma unroll
    for (int i = 0; i < NACC; ++i) s_part[wave][i] = a[i];
  }
  __syncthreads();
  if (threadIdx.x < NACC) {
    float v = 0.0f;
#pragma unroll
    for (int w = 0; w < THREADS / 64; ++w) v += s_part[w][threadIdx.x];
    // [bin][block] layout: no atomics, no zero-init of ws needed
    partial[(size_t)threadIdx.x * gridDim.x + blockIdx.x] = v;
  }
}

__global__ __launch_bounds__(1024) void ece_final(
    const float* __restrict__ partial, const float* __restrict__ logits,
    const int* __restrict__ labels, float* __restrict__ out, int n, int nblocks) {
  __shared__ double sbin[NACC];
  const int wave = threadIdx.x >> 6;
  const int lane = threadIdx.x & 63;
  if (wave < NACC) {
    double v = 0.0;
    for (int i = lane; i < nblocks; i += 64)
      v += (double)partial[(size_t)wave * nblocks + i];
#pragma unroll
    for (int off = 32; off > 0; off >>= 1) v += __shfl_down(v, off, 64);
    if (lane == 0) sbin[wave] = v;
  }
  __syncthreads();
  if (threadIdx.x == 0) {
    float t[NACC];
#pragma unroll
    for (int i = 0; i < NACC; ++i) t[i] = 0.0f;
    for (int r = (n >> 2) << 2; r < n; ++r)  // tail rows (none for N=2^24)
      process_row(logits[3 * r], logits[3 * r + 1], logits[3 * r + 2], labels[r], t);
    double ece = 0.0;
#pragma unroll
    for (int b = 0; b < NACC; ++b) ece += fabs(sbin[b] + (double)t[b]);
    out[0] = (float)(ece / (double)n);
  }
}

extern "C" void kernel_launch(void* const* d_in, const int* in_sizes, int n_in,
                              void* d_out, int out_size, void* d_ws, size_t ws_size,
                              hipStream_t stream) {
  const float4* logits4 = (const float4*)d_in[0];
  const int4* labels4 = (const int4*)d_in[1];
  const int n = in_sizes[1];  // rows == number of labels
  float* partial = (float*)d_ws;  // [NACC][GRID] floats
  ece_main<<<GRID, THREADS, 0, stream>>>(logits4, labels4, partial, n);
  ece_final<<<1, 1024, 0, stream>>>(partial, (const float*)d_in[0],
                                    (const int*)d_in[1], (float*)d_out, n, GRID);
}